// Round 4
// baseline (163.983 us; speedup 1.0000x reference)
//
#include <hip/hip_runtime.h>

// Problem constants (from reference): B=16, C=1, H=1024, W=1024, fp32.
#define HH 1024
#define WW 1024
#define BAND 16          // rows per block; thread = 16 rows x float4 strip
#define NT 256

// ext_vector type so __builtin_nontemporal_load accepts it.
typedef __attribute__((ext_vector_type(4))) float f32x4;

__device__ __forceinline__ float fmax3(float a, float b, float c) {
    return fmaxf(a, fmaxf(b, c));
}

__device__ __forceinline__ float loss_elem(float x, float t, float dil) {
    // target/dilated are exactly binary {0,1}: weight = 1 + 4*dil + 15*t
    float w = fmaf(15.0f, t, fmaf(4.0f, dil, 1.0f));
    // BCE with logits: max(x,0) - x*t + log1p(exp(-|x|))
    float a  = fabsf(x);
    float sp = __logf(1.0f + __expf(-a));
    return w * (fmaxf(x, 0.0f) - x * t + sp);
}

// R13: R12 (nt burst, main <=40.3us) + BAND 8->16.
//   Model (from R10/R11 WRITE_SIZE=90MB anomaly + R12 nt win): the harness
//   leaves 256MiB of DIRTY poison in L2/L3; cached reads that allocate evict
//   dirty lines -> writeback tax competing with the read stream. nt loads
//   never allocate -> clean pure-HBM stream ~3.8 TB/s, MSHR-capped ->
//   only ISSUED BYTES matter.
//   BAND=16: 18 target rows per 16 output rows (12.5% halo) vs 10/8 (25%):
//   144 MiB -> 136 MiB issued (-5.6%). 1024 blocks at 4 blocks/CU
//   (launch_bounds floor) = exactly ONE co-resident generation.
//   RA will serialize the 34 in-flight loads to fit 128 VGPR — fine,
//   MSHR-capped anyway (R9 ran the cap at ~10 in flight/wave).
//   Decision rule: main >=40us here => bytes not binding => read roofline.
template <bool PER_WAVE>
__global__ __launch_bounds__(NT, 4) void dilatedweightBCE_main(
        const float* __restrict__ pred,
        const float* __restrict__ target,
        float* __restrict__ partial) {
    __shared__ float swave[NT / 64];

    const int t    = threadIdx.x;
    const int lane = t & 63;
    const int wv   = t >> 6;
    const int c    = t * 4;                  // column strip (NT*4 == WW)

    // --- XCD-contiguous swizzle: l -> (img, h0) ---
    const int l    = blockIdx.x;             // [0, 1024)
    const int xcd  = l & 7;
    const int j    = l >> 3;                 // [0, 128)
    const int img  = j >> 3;                 // [0, 16)
    const int slab = j & 7;                  // [0, 8)
    const int h0   = (xcd * 8 + slab) * BAND;    // XCD x owns rows [128x,128x+128)

    const float* timg = target + (size_t)img * HH * WW;
    const float* pimg = pred   + (size_t)img * HH * WW;
    const f32x4 zero = (f32x4)(0.0f);

    // ---- ALL 34 independent loads issued before any use (nontemporal) ----
    f32x4 tr[BAND + 2];                     // target rows h0-1 .. h0+BAND
    tr[0] = (h0 > 0)
          ? __builtin_nontemporal_load((const f32x4*)(timg + (size_t)(h0 - 1) * WW + c))
          : zero;
    #pragma unroll
    for (int r = 0; r < BAND; ++r)
        tr[r + 1] = __builtin_nontemporal_load(
            (const f32x4*)(timg + (size_t)(h0 + r) * WW + c));
    tr[BAND + 1] = (h0 + BAND < HH)
          ? __builtin_nontemporal_load((const f32x4*)(timg + (size_t)(h0 + BAND) * WW + c))
          : zero;

    f32x4 xr[BAND];                         // pred rows h0 .. h0+BAND-1
    #pragma unroll
    for (int r = 0; r < BAND; ++r)
        xr[r] = __builtin_nontemporal_load(
            (const f32x4*)(pimg + (size_t)(h0 + r) * WW + c));

    // ---- halo column for wave-boundary lanes (nt too: never allocate) ----
    float halo[BAND];
    #pragma unroll
    for (int r = 0; r < BAND; ++r) halo[r] = 0.0f;
    if (lane == 0 || lane == 63) {
        const int pc = (lane == 0) ? c - 1 : c + 4;
        if (pc >= 0 && pc < WW) {
            float hv[BAND + 2];
            hv[0] = (h0 > 0)
                  ? __builtin_nontemporal_load(timg + (size_t)(h0 - 1) * WW + pc) : 0.0f;
            #pragma unroll
            for (int r = 0; r < BAND; ++r)
                hv[r + 1] = __builtin_nontemporal_load(timg + (size_t)(h0 + r) * WW + pc);
            hv[BAND + 1] = (h0 + BAND < HH)
                  ? __builtin_nontemporal_load(timg + (size_t)(h0 + BAND) * WW + pc) : 0.0f;
            #pragma unroll
            for (int r = 0; r < BAND; ++r)
                halo[r] = fmax3(hv[r], hv[r + 1], hv[r + 2]);
        }
    }

    // ---- dilation + loss, row by row (row j needs only tr[j..j+2]) ----
    float s = 0.0f;
    #pragma unroll
    for (int r = 0; r < BAND; ++r) {
        f32x4 a = tr[r], m = tr[r + 1], d = tr[r + 2];
        float vmx = fmax3(a.x, m.x, d.x);
        float vmy = fmax3(a.y, m.y, d.y);
        float vmz = fmax3(a.z, m.z, d.z);
        float vmw = fmax3(a.w, m.w, d.w);

        float lft = __shfl_up(vmw, 1);
        float rgt = __shfl_down(vmx, 1);
        if (lane == 0)  lft = halo[r];
        if (lane == 63) rgt = halo[r];

        float d0 = fmax3(lft, vmx, vmy);
        float d1 = fmax3(vmx, vmy, vmz);
        float d2 = fmax3(vmy, vmz, vmw);
        float d3 = fmax3(vmz, vmw, rgt);

        f32x4 x = xr[r];
        s += loss_elem(x.x, m.x, d0);
        s += loss_elem(x.y, m.y, d1);
        s += loss_elem(x.z, m.z, d2);
        s += loss_elem(x.w, m.w, d3);
    }

    // ---- wave reduction ----
    #pragma unroll
    for (int off = 32; off > 0; off >>= 1)
        s += __shfl_down(s, off);

    if (PER_WAVE) {
        if (lane == 0)
            partial[(size_t)l * (NT / 64) + wv] = s;   // no barrier, no LDS
    } else {
        if (lane == 0) swave[wv] = s;
        __syncthreads();
        if (t == 0) {
            float tot = 0.0f;
            #pragma unroll
            for (int i = 0; i < NT / 64; ++i) tot += swave[i];
            partial[l] = tot;
        }
    }
}

__global__ __launch_bounds__(1024) void dilatedweightBCE_reduce(
        const float* __restrict__ partial,
        float* __restrict__ out,
        int npart4,            // number of float4 chunks
        float inv_n) {
    __shared__ float swave[16];
    const int t = threadIdx.x;

    float s = 0.0f;
    const float4* p4 = (const float4*)partial;
    for (int i = t; i < npart4; i += 1024) {
        float4 v = p4[i];
        s += v.x + v.y + v.z + v.w;
    }

    #pragma unroll
    for (int off = 32; off > 0; off >>= 1)
        s += __shfl_down(s, off);

    const int lane = t & 63;
    if (lane == 0) swave[t >> 6] = s;
    __syncthreads();
    if (t == 0) {
        float tot = 0.0f;
        #pragma unroll
        for (int i = 0; i < 16; ++i) tot += swave[i];
        out[0] = tot * inv_n;
    }
}

extern "C" void kernel_launch(void* const* d_in, const int* in_sizes, int n_in,
                              void* d_out, int out_size, void* d_ws, size_t ws_size,
                              hipStream_t stream) {
    const float* pred   = (const float*)d_in[0];
    const float* target = (const float*)d_in[1];
    float* out     = (float*)d_out;
    float* partial = (float*)d_ws;

    const int n  = in_sizes[0];              // B*C*H*W
    const int Bn = n / (HH * WW);            // batch (16)
    const int nblocks = (HH / BAND) * Bn;    // 1024

    const size_t need = (size_t)nblocks * (NT / 64) * sizeof(float);  // 16 KB
    if (ws_size >= need) {
        dilatedweightBCE_main<true><<<nblocks, NT, 0, stream>>>(pred, target, partial);
        dilatedweightBCE_reduce<<<1, 1024, 0, stream>>>(partial, out,
                                                        nblocks * (NT / 64) / 4,
                                                        1.0f / (float)n);
    } else {
        dilatedweightBCE_main<false><<<nblocks, NT, 0, stream>>>(pred, target, partial);
        dilatedweightBCE_reduce<<<1, 1024, 0, stream>>>(partial, out,
                                                        nblocks / 4,
                                                        1.0f / (float)n);
    }
}